// Round 17
// baseline (98.321 us; speedup 1.0000x reference)
//
#include <hip/hip_runtime.h>

typedef __attribute__((ext_vector_type(4))) float f32x4;
typedef __attribute__((ext_vector_type(8))) __bf16 bf16x8;
typedef __attribute__((ext_vector_type(4))) unsigned short us4;
typedef __attribute__((ext_vector_type(8))) unsigned short us8;

#define DEVI static __device__ __forceinline__

constexpr int T_ = 2048, E_ = 1024, H_ = 16, D_ = 64;
#define QSCALE (0.125f * 1.44269504088896f)  /* 1/sqrt(D) * log2(e) */

DEVI unsigned short f2b(float f) {
  union { __bf16 b; unsigned short u; } c; c.b = (__bf16)f; return c.u;
}

DEVI unsigned pkw(float a, float b) {  // pack 2 f32 -> 2 bf16 in one u32
  union { __bf16 h[2]; unsigned u; } c;
  c.h[0] = (__bf16)a; c.h[1] = (__bf16)b; return c.u;
}

#if __has_builtin(__builtin_amdgcn_exp2f)
DEVI float fexp2(float x) { return __builtin_amdgcn_exp2f(x); }
#else
DEVI float fexp2(float x) { return __expf(x * 0.69314718056f); }
#endif

DEVI f32x4 mfma16(bf16x8 a, bf16x8 b, f32x4 c) {
  return __builtin_amdgcn_mfma_f32_16x16x32_bf16(a, b, c, 0, 0, 0);
}

// ---------------- single weight-conversion kernel (run once, first) ----------------
// blocks [0,64)=Wq (scaled), [64,128)=Wk, [128,192)=Wv, [192,1216)=Wp
__launch_bounds__(256)
__global__ void cvt_kernel(const float* __restrict__ Wq,
                           const float* __restrict__ Wk,
                           const float* __restrict__ Wv,
                           const float* __restrict__ Wp,
                           unsigned short* __restrict__ wqb,
                           unsigned short* __restrict__ wkb,
                           unsigned short* __restrict__ wvb,
                           unsigned short* __restrict__ wpb)
{
  int blk = blockIdx.x;
  const float* src; unsigned short* dst; float s = 1.0f;
  if (blk < 64)       { src = Wq; dst = wqb; s = QSCALE; }
  else if (blk < 128) { src = Wk; dst = wkb; blk -= 64; }
  else if (blk < 192) { src = Wv; dst = wvb; blk -= 128; }
  else                { src = Wp; dst = wpb; blk -= 192; }
  int i = blk * 256 + threadIdx.x;
  float4 v = *(const float4*)(src + (size_t)i * 4);
  us4 o; o[0] = f2b(v.x * s); o[1] = f2b(v.y * s); o[2] = f2b(v.z * s); o[3] = f2b(v.w * s);
  *(us4*)(dst + (size_t)i * 4) = o;
}

// ---------------- QKV projection (r14 verbatim): W from pre-converted bf16 ----------------
__launch_bounds__(256)
__global__ void qkv_kernel(const float* __restrict__ x,
                           const unsigned short* __restrict__ wqb,
                           const float* __restrict__ bq,
                           const unsigned short* __restrict__ wkb,
                           const float* __restrict__ bk,
                           const unsigned short* __restrict__ wvb,
                           const float* __restrict__ bv,
                           unsigned short* __restrict__ qo,
                           unsigned short* __restrict__ ko,
                           unsigned short* __restrict__ vto)
{
  const int bh = blockIdx.x;
  const int b  = bh >> 4;
  const int h  = bh & (H_ - 1);
  const int t0 = blockIdx.y * 128;
  __shared__ unsigned short Xl[128][72];
  const int tid = threadIdx.x;

  #pragma unroll
  for (int p = 0; p < 8; ++p) {
    int idx = p * 256 + tid;
    int row = idx >> 4, c4 = idx & 15;
    float4 v = *(const float4*)(x + ((size_t)(b * T_ + t0 + row)) * E_ + h * 64 + c4 * 4);
    us4 o; o[0] = f2b(v.x); o[1] = f2b(v.y); o[2] = f2b(v.z); o[3] = f2b(v.w);
    *(us4*)&Xl[row][c4 * 4] = o;
  }
  __syncthreads();

  const int w = tid >> 6, lane = tid & 63, lo = lane & 15, g = lane >> 4;
  const int tl0 = w * 32;

  bf16x8 xb[2][2];
  #pragma unroll
  for (int tt = 0; tt < 2; ++tt)
    #pragma unroll
    for (int kd = 0; kd < 2; ++kd)
      xb[tt][kd] = *(const bf16x8*)&Xl[tl0 + tt * 16 + lo][kd * 32 + g * 8];

  #pragma unroll
  for (int tsel = 0; tsel < 2; ++tsel) {
    const float* bias = tsel ? bk : bq;
    unsigned short* outp = tsel ? ko : qo;
    const unsigned short* wsrc = (tsel ? wkb : wqb) + (size_t)h * 4096;
    const float bs = tsel ? 1.0f : QSCALE;
    #pragma unroll
    for (int ot = 0; ot < 4; ++ot) {
      bf16x8 a0 = *(const bf16x8*)(wsrc + (ot * 16 + lo) * 64 + g * 8);
      bf16x8 a1 = *(const bf16x8*)(wsrc + (ot * 16 + lo) * 64 + 32 + g * 8);
      float4 bv4 = *(const float4*)(bias + h * 64 + ot * 16 + g * 4);
      float bb[4] = {bv4.x * bs, bv4.y * bs, bv4.z * bs, bv4.w * bs};
      #pragma unroll
      for (int tt = 0; tt < 2; ++tt) {
        f32x4 acc = {0.f, 0.f, 0.f, 0.f};
        acc = mfma16(a0, xb[tt][0], acc);
        acc = mfma16(a1, xb[tt][1], acc);
        int tg = t0 + tl0 + tt * 16 + lo;
        us4 pk;
        #pragma unroll
        for (int r = 0; r < 4; ++r) pk[r] = f2b(acc[r] + bb[r]);
        *(us4*)(outp + ((size_t)(bh * T_ + tg)) * 64 + ot * 16 + g * 4) = pk;
      }
    }
  }

  {
    const unsigned short* wsrc2 = wvb + (size_t)h * 4096;
    #pragma unroll
    for (int rt = 0; rt < 2; ++rt) {
      bf16x8 a0 = *(const bf16x8*)&Xl[tl0 + rt * 16 + lo][g * 8];
      bf16x8 a1 = *(const bf16x8*)&Xl[tl0 + rt * 16 + lo][32 + g * 8];
      #pragma unroll
      for (int ct = 0; ct < 4; ++ct) {
        bf16x8 b0 = *(const bf16x8*)(wsrc2 + (ct * 16 + lo) * 64 + g * 8);
        bf16x8 b1 = *(const bf16x8*)(wsrc2 + (ct * 16 + lo) * 64 + 32 + g * 8);
        f32x4 acc = {0.f, 0.f, 0.f, 0.f};
        acc = mfma16(a0, b0, acc);
        acc = mfma16(a1, b1, acc);
        int d = ct * 16 + lo;
        float bvs = bv[h * 64 + d];
        int tg = t0 + tl0 + rt * 16 + g * 4;
        us4 pk;
        #pragma unroll
        for (int r = 0; r < 4; ++r) pk[r] = f2b(acc[r] + bvs);
        *(us4*)(vto + ((size_t)(bh * 64 + d)) * T_ + tg) = pk;
      }
    }
  }
}

// ---------------- causal flash attention: PAIRED (2 problems per block) ----------------
// 1-D grid 512, block 256 = 4 waves x 16 q-rows. Block id: pr = id&15,
// qt = 31-(id>>4) (heavy first). Each block runs the SAME q-tile for TWO
// (b,h) problems: bh0=pr (b=0), bh1=pr+16 (b=1) — two independent dependency
// chains per wave fill each other's stall slots. Per-problem math = r10
// verbatim (rho-K + sigma-V, deferred PV, in-register P, ones-MFMA l).
// LDS 80KB -> 2 blocks/CU (matches measured residency).
__launch_bounds__(256)
__global__ void flash_kernel(const unsigned short* __restrict__ q,
                             const unsigned short* __restrict__ kk_,
                             const unsigned short* __restrict__ vt,
                             unsigned short* __restrict__ ao)
{
  const int id = blockIdx.x;
  const int pr = id & 15;
  const int qt = 31 - (id >> 4);
  const int t0 = qt * 64;
  __shared__ unsigned short Kl[2][2][64][64];   // [pp][dbuf]
  __shared__ unsigned short Vl[2][3][64][64];   // [pp][tbuf]
  const int tid = threadIdx.x, w = tid >> 6, lane = tid & 63, lo = lane & 15, g = lane >> 4;
  const int rs = lo & 7;

  // staging decomposition (r10-verified rho/sigma)
  const int srow = tid >> 3, sgi = tid & 7;
  const int khalf = (srow >> 2) & 1;
  const int gsrc = (srow >> 3) ^ (khalf << 1);
  const int prow = khalf * 16 + gsrc * 4 + (srow & 3);
  const int kkey = (sgi ^ (prow & 7)) * 8;
  const int vkey = (sgi ^ (srow & 7)) * 8;
  const int vco0 = sgi * 8;
  const int vco1 = ((sgi ^ 2) * 8) + 4;

  const unsigned short* kbase[2];
  const unsigned short* vrow0[2];
  const unsigned short* vrow1[2];
  #pragma unroll
  for (int pp = 0; pp < 2; ++pp) {
    const int bh = pr + pp * 16;
    kbase[pp] = kk_ + ((size_t)bh * T_ + srow) * 64 + sgi * 8;
    vrow0[pp] = vt + ((size_t)(bh * 64 + srow)) * T_;
    vrow1[pp] = vrow0[pp] + (size_t)32 * T_;
  }

  const int tw = t0 + w * 16;

  bf16x8 qf[2][2];
  #pragma unroll
  for (int pp = 0; pp < 2; ++pp) {
    const int bh = pr + pp * 16;
    const unsigned short* qb = q + ((size_t)(bh * T_ + tw + lo)) * 64;
    #pragma unroll
    for (int kd = 0; kd < 2; ++kd)
      qf[pp][kd] = *(const bf16x8*)(qb + kd * 32 + g * 8);
  }

  const int sb0 = g * 8, sb1 = ((g ^ 2) * 8) + 4;

  union { unsigned u[4]; bf16x8 v; } onec;
  onec.u[0] = onec.u[1] = onec.u[2] = onec.u[3] = 0x3f803f80u;
  const bf16x8 onesv = onec.v;

  float m_[2] = {-1e30f, -1e30f};
  f32x4 zero4 = {0.f, 0.f, 0.f, 0.f};
  f32x4 lacc[2] = {zero4, zero4};
  f32x4 oacc[2][4];
  #pragma unroll
  for (int pp = 0; pp < 2; ++pp)
    #pragma unroll
    for (int dt = 0; dt < 4; ++dt) oacc[pp][dt] = zero4;

  const int nsteps = qt + 1;
  union u8c { us4 h4[2]; us8 v; };
  us8 kr0[2], kr1[2];
  u8c vr0[2], vr1[2];
  // prologue: stage step 0 (both problems); preload step-1 regs
  #pragma unroll
  for (int pp = 0; pp < 2; ++pp) {
    kr0[pp] = *(const us8*)(kbase[pp]);
    kr1[pp] = *(const us8*)(kbase[pp] + 2048);
    vr0[pp].h4[0] = *(const us4*)(vrow0[pp] + vco0);
    vr0[pp].h4[1] = *(const us4*)(vrow0[pp] + vco1);
    vr1[pp].h4[0] = *(const us4*)(vrow1[pp] + vco0);
    vr1[pp].h4[1] = *(const us4*)(vrow1[pp] + vco1);
    *(us8*)&Kl[pp][0][prow][kkey] = kr0[pp];
    *(us8*)&Kl[pp][0][prow + 32][kkey] = kr1[pp];
    *(us8*)&Vl[pp][0][srow][vkey] = vr0[pp].v;
    *(us8*)&Vl[pp][0][srow + 32][vkey] = vr1[pp].v;
  }
  if (nsteps > 1) {
    #pragma unroll
    for (int pp = 0; pp < 2; ++pp) {
      kr0[pp] = *(const us8*)(kbase[pp] + 4096);
      kr1[pp] = *(const us8*)(kbase[pp] + 4096 + 2048);
      vr0[pp].h4[0] = *(const us4*)(vrow0[pp] + 64 + vco0);
      vr0[pp].h4[1] = *(const us4*)(vrow0[pp] + 64 + vco1);
      vr1[pp].h4[0] = *(const us4*)(vrow1[pp] + 64 + vco0);
      vr1[pp].h4[1] = *(const us4*)(vrow1[pp] + 64 + vco1);
    }
  }
  __syncthreads();

  bf16x8 pb[2][2];   // [pp][kh]
  int vprev = 0;

  for (int stp = 0; stp < nsteps; ++stp) {
    const int cur = stp & 1;
    us8 nk0[2], nk1[2];
    u8c nv0[2], nv1[2];
    const bool pf = (stp + 2 < nsteps);
    if (pf) {
      const size_t ko_ = (size_t)(stp + 2) * 4096;
      const int so = (stp + 2) * 64;
      #pragma unroll
      for (int pp = 0; pp < 2; ++pp) {
        nk0[pp] = *(const us8*)(kbase[pp] + ko_);
        nk1[pp] = *(const us8*)(kbase[pp] + ko_ + 2048);
        nv0[pp].h4[0] = *(const us4*)(vrow0[pp] + so + vco0);
        nv0[pp].h4[1] = *(const us4*)(vrow0[pp] + so + vco1);
        nv1[pp].h4[0] = *(const us4*)(vrow1[pp] + so + vco0);
        nv1[pp].h4[1] = *(const us4*)(vrow1[pp] + so + vco1);
      }
    }
    // ---- MFMA cluster: QK^T(stp) x2 + PV(stp-1) x2 ----
    f32x4 sacc[2][4];
    #pragma unroll
    for (int pp = 0; pp < 2; ++pp)
      #pragma unroll
      for (int ss = 0; ss < 4; ++ss) sacc[pp][ss] = zero4;
    __builtin_amdgcn_s_setprio(1);
    #pragma unroll
    for (int pp = 0; pp < 2; ++pp) {
      #pragma unroll
      for (int ss = 0; ss < 4; ++ss) {
        bf16x8 ka0 = *(const bf16x8*)&Kl[pp][cur][ss * 16 + lo][(g ^ rs) * 8];
        bf16x8 ka1 = *(const bf16x8*)&Kl[pp][cur][ss * 16 + lo][((g | 4) ^ rs) * 8];
        sacc[pp][ss] = mfma16(ka0, qf[pp][0], sacc[pp][ss]);
        sacc[pp][ss] = mfma16(ka1, qf[pp][1], sacc[pp][ss]);
      }
    }
    if (stp > 0) {
      #pragma unroll
      for (int pp = 0; pp < 2; ++pp)
        #pragma unroll
        for (int kh = 0; kh < 2; ++kh)
          #pragma unroll
          for (int dt = 0; dt < 4; ++dt) {
            bf16x8 va = *(const bf16x8*)&Vl[pp][vprev][dt * 16 + lo][((kh * 4 + g) ^ rs) * 8];
            oacc[pp][dt] = mfma16(va, pb[pp][kh], oacc[pp][dt]);
          }
    }
    __builtin_amdgcn_s_setprio(0);
    // ---- softmax (both problems; independent VALU chains) ----
    if (stp == nsteps - 1) {  // diagonal step: causal mask (de-permuted s)
      #pragma unroll
      for (int pp = 0; pp < 2; ++pp)
        #pragma unroll
        for (int ss = 0; ss < 4; ++ss) {
          const int sb = ((ss & 1) ? sb1 : sb0) + (ss >> 1) * 32;
          #pragma unroll
          for (int r = 0; r < 4; ++r) {
            if (t0 + sb + r > tw + lo) sacc[pp][ss][r] = -1e30f;
          }
        }
    }
    #pragma unroll
    for (int pp = 0; pp < 2; ++pp) {
      float mx = -1e30f;
      #pragma unroll
      for (int ss = 0; ss < 4; ++ss) {
        float a = fmaxf(sacc[pp][ss][0], sacc[pp][ss][1]);
        float c = fmaxf(sacc[pp][ss][2], sacc[pp][ss][3]);
        mx = fmaxf(mx, fmaxf(a, c));
      }
      if (!__all(mx <= m_[pp] + 8.0f)) {  // rare rescale (wave-uniform)
        mx = fmaxf(mx, __shfl_xor(mx, 16));
        mx = fmaxf(mx, __shfl_xor(mx, 32));
        float mn = fmaxf(m_[pp], mx);
        float corr = fexp2(m_[pp] - mn);
        m_[pp] = mn;
        lacc[pp] *= corr;
        #pragma unroll
        for (int dt = 0; dt < 4; ++dt) oacc[pp][dt] *= corr;
      }
      #pragma unroll
      for (int kh = 0; kh < 2; ++kh) {
        union { unsigned u[4]; bf16x8 v; } pbc;
        #pragma unroll
        for (int half2 = 0; half2 < 2; ++half2) {
          const int ss = kh * 2 + half2;
          float p0 = fexp2(sacc[pp][ss][0] - m_[pp]);
          float p1 = fexp2(sacc[pp][ss][1] - m_[pp]);
          float p2 = fexp2(sacc[pp][ss][2] - m_[pp]);
          float p3 = fexp2(sacc[pp][ss][3] - m_[pp]);
          pbc.u[half2 * 2]     = pkw(p0, p1);
          pbc.u[half2 * 2 + 1] = pkw(p2, p3);
        }
        pb[pp][kh] = pbc.v;
        lacc[pp] = mfma16(onesv, pb[pp][kh], lacc[pp]);
      }
    }
    vprev = stp % 3;
    // stage next K/V tiles (both problems)
    if (stp + 1 < nsteps) {
      const int vn = (stp + 1) % 3;
      #pragma unroll
      for (int pp = 0; pp < 2; ++pp) {
        *(us8*)&Kl[pp][cur ^ 1][prow][kkey] = kr0[pp];
        *(us8*)&Kl[pp][cur ^ 1][prow + 32][kkey] = kr1[pp];
        *(us8*)&Vl[pp][vn][srow][vkey] = vr0[pp].v;
        *(us8*)&Vl[pp][vn][srow + 32][vkey] = vr1[pp].v;
      }
    }
    __syncthreads();
    if (pf) {
      #pragma unroll
      for (int pp = 0; pp < 2; ++pp) {
        kr0[pp] = nk0[pp]; kr1[pp] = nk1[pp];
        vr0[pp] = nv0[pp]; vr1[pp] = nv1[pp];
      }
    }
  }
  // epilogue: drain PV(last), write both outputs
  __builtin_amdgcn_s_setprio(1);
  #pragma unroll
  for (int pp = 0; pp < 2; ++pp)
    #pragma unroll
    for (int kh = 0; kh < 2; ++kh)
      #pragma unroll
      for (int dt = 0; dt < 4; ++dt) {
        bf16x8 va = *(const bf16x8*)&Vl[pp][vprev][dt * 16 + lo][((kh * 4 + g) ^ rs) * 8];
        oacc[pp][dt] = mfma16(va, pb[pp][kh], oacc[pp][dt]);
      }
  __builtin_amdgcn_s_setprio(0);
  #pragma unroll
  for (int pp = 0; pp < 2; ++pp) {
    const int b = pp, h = pr;
    float inv = 1.0f / lacc[pp][0];
    unsigned short* op = ao + ((size_t)(b * T_ + tw + lo)) * E_ + h * 64;
    #pragma unroll
    for (int dt = 0; dt < 4; ++dt) {
      us4 pk;
      #pragma unroll
      for (int r = 0; r < 4; ++r) pk[r] = f2b(oacc[pp][dt][r] * inv);
      *(us4*)(op + dt * 16 + g * 4) = pk;
    }
  }
}

// ---------------- output projection (r14 verbatim: BK=64, XCD-partitioned) ----------------
__launch_bounds__(256)
__global__ void proj_kernel(const unsigned short* __restrict__ ao,
                            const unsigned short* __restrict__ wpb,
                            const float* __restrict__ bp,
                            float* __restrict__ out)
{
  const int bid = blockIdx.x;
  const int xcd = bid & 7, idx = bid >> 3;
  const int m0 = (xcd * 4 + (idx & 3)) * 128;
  const int n0 = (idx >> 2) * 64;
  __shared__ unsigned short Al[2][128][72];
  __shared__ unsigned short Bl[2][64][72];
  const int tid = threadIdx.x, w = tid >> 6, lane = tid & 63, lo = lane & 15, g = lane >> 4;
  const int wr = (w >> 1) * 64, wc = (w & 1) * 32;
  f32x4 zero4 = {0.f, 0.f, 0.f, 0.f};
  f32x4 acc[4][2];
  #pragma unroll
  for (int i = 0; i < 4; ++i)
    #pragma unroll
    for (int j = 0; j < 2; ++j) acc[i][j] = zero4;

  const int arow = tid >> 1, acol = (tid & 1) * 32;
  const int brow = tid >> 2, bcol = (tid & 3) * 16;
  const unsigned short* abase = ao + (size_t)(m0 + arow) * 1024 + acol;
  const unsigned short* bbase = wpb + (size_t)(n0 + brow) * 1024 + bcol;

  us8 a0, a1, a2, a3, b0, b1;
  a0 = *(const us8*)(abase);
  a1 = *(const us8*)(abase + 8);
  a2 = *(const us8*)(abase + 16);
  a3 = *(const us8*)(abase + 24);
  b0 = *(const us8*)(bbase);
  b1 = *(const us8*)(bbase + 8);
  *(us8*)&Al[0][arow][acol] = a0;
  *(us8*)&Al[0][arow][acol + 8] = a1;
  *(us8*)&Al[0][arow][acol + 16] = a2;
  *(us8*)&Al[0][arow][acol + 24] = a3;
  *(us8*)&Bl[0][brow][bcol] = b0;
  *(us8*)&Bl[0][brow][bcol + 8] = b1;
  a0 = *(const us8*)(abase + 64);
  a1 = *(const us8*)(abase + 72);
  a2 = *(const us8*)(abase + 80);
  a3 = *(const us8*)(abase + 88);
  b0 = *(const us8*)(bbase + 64);
  b1 = *(const us8*)(bbase + 72);
  __syncthreads();

  for (int it = 0; it < 16; ++it) {
    const int cur = it & 1;
    us8 na0, na1, na2, na3, nb0, nb1;
    const bool pf = (it + 2 < 16);
    if (pf) {
      const int kn = (it + 2) * 64;
      na0 = *(const us8*)(abase + kn);
      na1 = *(const us8*)(abase + kn + 8);
      na2 = *(const us8*)(abase + kn + 16);
      na3 = *(const us8*)(abase + kn + 24);
      nb0 = *(const us8*)(bbase + kn);
      nb1 = *(const us8*)(bbase + kn + 8);
    }
    bf16x8 af[4][2], bfr[2][2];
    #pragma unroll
    for (int kk = 0; kk < 2; ++kk) {
      #pragma unroll
      for (int i = 0; i < 4; ++i)
        af[i][kk] = *(const bf16x8*)&Al[cur][wr + i * 16 + lo][kk * 32 + g * 8];
      #pragma unroll
      for (int j = 0; j < 2; ++j)
        bfr[j][kk] = *(const bf16x8*)&Bl[cur][wc + j * 16 + lo][kk * 32 + g * 8];
    }
    __builtin_amdgcn_s_setprio(1);
    #pragma unroll
    for (int kk = 0; kk < 2; ++kk)
      #pragma unroll
      for (int i = 0; i < 4; ++i)
        #pragma unroll
        for (int j = 0; j < 2; ++j)
          acc[i][j] = mfma16(af[i][kk], bfr[j][kk], acc[i][j]);
    __builtin_amdgcn_s_setprio(0);
    if (it + 1 < 16) {
      *(us8*)&Al[cur ^ 1][arow][acol] = a0;
      *(us8*)&Al[cur ^ 1][arow][acol + 8] = a1;
      *(us8*)&Al[cur ^ 1][arow][acol + 16] = a2;
      *(us8*)&Al[cur ^ 1][arow][acol + 24] = a3;
      *(us8*)&Bl[cur ^ 1][brow][bcol] = b0;
      *(us8*)&Bl[cur ^ 1][brow][bcol + 8] = b1;
    }
    __syncthreads();
    if (pf) { a0 = na0; a1 = na1; a2 = na2; a3 = na3; b0 = nb0; b1 = nb1; }
  }
  #pragma unroll
  for (int j = 0; j < 2; ++j) {
    int n = n0 + wc + j * 16 + lo;
    float bias = bp[n];
    #pragma unroll
    for (int i = 0; i < 4; ++i) {
      #pragma unroll
      for (int r = 0; r < 4; ++r)
        out[(size_t)(m0 + wr + i * 16 + g * 4 + r) * 1024 + n] = acc[i][j][r] + bias;
    }
  }
}

extern "C" void kernel_launch(void* const* d_in, const int* in_sizes, int n_in,
                              void* d_out, int out_size, void* d_ws, size_t ws_size,
                              hipStream_t stream)
{
  const float* x  = (const float*)d_in[0];
  const float* Wq = (const float*)d_in[2];
  const float* bq = (const float*)d_in[3];
  const float* Wk = (const float*)d_in[4];
  const float* bk = (const float*)d_in[5];
  const float* Wv = (const float*)d_in[6];
  const float* bv = (const float*)d_in[7];
  const float* Wp = (const float*)d_in[8];
  const float* bp = (const float*)d_in[9];
  float* out = (float*)d_out;

  char* ws = (char*)d_ws;
  const size_t SZ = (size_t)2 * 16 * 2048 * 64 * 2;  // 8 MB per bf16 tensor
  unsigned short* q   = (unsigned short*)(ws);
  unsigned short* kb  = (unsigned short*)(ws + SZ);
  unsigned short* vt  = (unsigned short*)(ws + 2 * SZ);
  unsigned short* ao  = (unsigned short*)(ws + 3 * SZ);
  unsigned short* wpb = (unsigned short*)(ws + 4 * SZ);            // 2 MB
  unsigned short* wqb = (unsigned short*)(ws + 4 * SZ + 2097152);  // 128 KB each
  unsigned short* wkb = wqb + 65536;
  unsigned short* wvb = wqb + 131072;

  cvt_kernel<<<dim3(1216), 256, 0, stream>>>(Wq, Wk, Wv, Wp, wqb, wkb, wvb, wpb);
  qkv_kernel<<<dim3(32, 16), 256, 0, stream>>>(x, wqb, bq, wkb, bk, wvb, bv, q, kb, vt);
  flash_kernel<<<dim3(512), 256, 0, stream>>>(q, kb, vt, ao);
  proj_kernel<<<dim3(512), 256, 0, stream>>>(ao, wpb, bp, out);
}

// Round 18
// 78.483 us; speedup vs baseline: 1.2528x; 1.2528x over previous
//
#include <hip/hip_runtime.h>

typedef __attribute__((ext_vector_type(4))) float f32x4;
typedef __attribute__((ext_vector_type(8))) __bf16 bf16x8;
typedef __attribute__((ext_vector_type(4))) unsigned short us4;
typedef __attribute__((ext_vector_type(8))) unsigned short us8;

#define DEVI static __device__ __forceinline__

constexpr int T_ = 2048, E_ = 1024, H_ = 16, D_ = 64;
#define QSCALE (0.125f * 1.44269504088896f)  /* 1/sqrt(D) * log2(e) */

DEVI unsigned short f2b(float f) {
  union { __bf16 b; unsigned short u; } c; c.b = (__bf16)f; return c.u;
}

DEVI unsigned pkw(float a, float b) {  // pack 2 f32 -> 2 bf16 in one u32
  union { __bf16 h[2]; unsigned u; } c;
  c.h[0] = (__bf16)a; c.h[1] = (__bf16)b; return c.u;
}

#if __has_builtin(__builtin_amdgcn_exp2f)
DEVI float fexp2(float x) { return __builtin_amdgcn_exp2f(x); }
#else
DEVI float fexp2(float x) { return __expf(x * 0.69314718056f); }
#endif

DEVI f32x4 mfma16(bf16x8 a, bf16x8 b, f32x4 c) {
  return __builtin_amdgcn_mfma_f32_16x16x32_bf16(a, b, c, 0, 0, 0);
}

// ---------------- single weight-conversion kernel (run once, first) ----------------
// blocks [0,64)=Wq (scaled), [64,128)=Wk, [128,192)=Wv, [192,1216)=Wp
__launch_bounds__(256)
__global__ void cvt_kernel(const float* __restrict__ Wq,
                           const float* __restrict__ Wk,
                           const float* __restrict__ Wv,
                           const float* __restrict__ Wp,
                           unsigned short* __restrict__ wqb,
                           unsigned short* __restrict__ wkb,
                           unsigned short* __restrict__ wvb,
                           unsigned short* __restrict__ wpb)
{
  int blk = blockIdx.x;
  const float* src; unsigned short* dst; float s = 1.0f;
  if (blk < 64)       { src = Wq; dst = wqb; s = QSCALE; }
  else if (blk < 128) { src = Wk; dst = wkb; blk -= 64; }
  else if (blk < 192) { src = Wv; dst = wvb; blk -= 128; }
  else                { src = Wp; dst = wpb; blk -= 192; }
  int i = blk * 256 + threadIdx.x;
  float4 v = *(const float4*)(src + (size_t)i * 4);
  us4 o; o[0] = f2b(v.x * s); o[1] = f2b(v.y * s); o[2] = f2b(v.z * s); o[3] = f2b(v.w * s);
  *(us4*)(dst + (size_t)i * 4) = o;
}

// ---------------- QKV projection v2: W fragments direct from global (L2-hot) ----------------
// grid: (B*H=32, T/128=16), block 256 (4 waves x 32 rows); LDS = Xl only (18KB)
__launch_bounds__(256)
__global__ void qkv_kernel(const float* __restrict__ x,
                           const unsigned short* __restrict__ wqb,
                           const float* __restrict__ bq,
                           const unsigned short* __restrict__ wkb,
                           const float* __restrict__ bk,
                           const unsigned short* __restrict__ wvb,
                           const float* __restrict__ bv,
                           unsigned short* __restrict__ qo,
                           unsigned short* __restrict__ ko,
                           unsigned short* __restrict__ vto)
{
  const int bh = blockIdx.x;
  const int b  = bh >> 4;
  const int h  = bh & (H_ - 1);
  const int t0 = blockIdx.y * 128;
  __shared__ unsigned short Xl[128][72];
  const int tid = threadIdx.x;

  #pragma unroll
  for (int p = 0; p < 8; ++p) {
    int idx = p * 256 + tid;
    int row = idx >> 4, c4 = idx & 15;
    float4 v = *(const float4*)(x + ((size_t)(b * T_ + t0 + row)) * E_ + h * 64 + c4 * 4);
    us4 o; o[0] = f2b(v.x); o[1] = f2b(v.y); o[2] = f2b(v.z); o[3] = f2b(v.w);
    *(us4*)&Xl[row][c4 * 4] = o;
  }
  __syncthreads();

  const int w = tid >> 6, lane = tid & 63, lo = lane & 15, g = lane >> 4;
  const int tl0 = w * 32;

  bf16x8 xb[2][2];
  #pragma unroll
  for (int tt = 0; tt < 2; ++tt)
    #pragma unroll
    for (int kd = 0; kd < 2; ++kd)
      xb[tt][kd] = *(const bf16x8*)&Xl[tl0 + tt * 16 + lo][kd * 32 + g * 8];

  // Q and K: C = W * X^T  (o x t); W A-fragments read directly from global
  #pragma unroll
  for (int tsel = 0; tsel < 2; ++tsel) {
    const float* bias = tsel ? bk : bq;
    unsigned short* outp = tsel ? ko : qo;
    const unsigned short* wsrc = (tsel ? wkb : wqb) + (size_t)h * 4096;
    const float bs = tsel ? 1.0f : QSCALE;
    #pragma unroll
    for (int ot = 0; ot < 4; ++ot) {
      bf16x8 a0 = *(const bf16x8*)(wsrc + (ot * 16 + lo) * 64 + g * 8);
      bf16x8 a1 = *(const bf16x8*)(wsrc + (ot * 16 + lo) * 64 + 32 + g * 8);
      float4 bv4 = *(const float4*)(bias + h * 64 + ot * 16 + g * 4);
      float bb[4] = {bv4.x * bs, bv4.y * bs, bv4.z * bs, bv4.w * bs};
      #pragma unroll
      for (int tt = 0; tt < 2; ++tt) {
        f32x4 acc = {0.f, 0.f, 0.f, 0.f};
        acc = mfma16(a0, xb[tt][0], acc);
        acc = mfma16(a1, xb[tt][1], acc);
        int tg = t0 + tl0 + tt * 16 + lo;
        us4 pk;
        #pragma unroll
        for (int r = 0; r < 4; ++r) pk[r] = f2b(acc[r] + bb[r]);
        *(us4*)(outp + ((size_t)(bh * T_ + tg)) * 64 + ot * 16 + g * 4) = pk;
      }
    }
  }

  // V: C = X * W^T (t x o); W B-fragments direct from global
  {
    const unsigned short* wsrc2 = wvb + (size_t)h * 4096;
    #pragma unroll
    for (int rt = 0; rt < 2; ++rt) {
      bf16x8 a0 = *(const bf16x8*)&Xl[tl0 + rt * 16 + lo][g * 8];
      bf16x8 a1 = *(const bf16x8*)&Xl[tl0 + rt * 16 + lo][32 + g * 8];
      #pragma unroll
      for (int ct = 0; ct < 4; ++ct) {
        bf16x8 b0 = *(const bf16x8*)(wsrc2 + (ct * 16 + lo) * 64 + g * 8);
        bf16x8 b1 = *(const bf16x8*)(wsrc2 + (ct * 16 + lo) * 64 + 32 + g * 8);
        f32x4 acc = {0.f, 0.f, 0.f, 0.f};
        acc = mfma16(a0, b0, acc);
        acc = mfma16(a1, b1, acc);
        int d = ct * 16 + lo;
        float bvs = bv[h * 64 + d];
        int tg = t0 + tl0 + rt * 16 + g * 4;
        us4 pk;
        #pragma unroll
        for (int r = 0; r < 4; ++r) pk[r] = f2b(acc[r] + bvs);
        *(us4*)(vto + ((size_t)(bh * 64 + d)) * T_ + tg) = pk;
      }
    }
  }
}

// ---------------- causal flash attention (r10 verbatim, best known: 43.2us) ----------------
__launch_bounds__(256)
__global__ void flash_kernel(const unsigned short* __restrict__ q,
                             const unsigned short* __restrict__ kk_,
                             const unsigned short* __restrict__ vt,
                             unsigned short* __restrict__ ao)
{
  const int bh = blockIdx.x;
  const int b = bh >> 4, h = bh & 15;
  const int qt = 31 - blockIdx.y;
  const int t0 = qt * 64;
  __shared__ unsigned short Kl[2][64][64];
  __shared__ unsigned short Vl[3][64][64];
  const int tid = threadIdx.x, w = tid >> 6, lane = tid & 63, lo = lane & 15, g = lane >> 4;
  const int rs = lo & 7;

  const int srow = tid >> 3, sgi = tid & 7;
  const int khalf = (srow >> 2) & 1;
  const int gsrc = (srow >> 3) ^ (khalf << 1);
  const int prow = khalf * 16 + gsrc * 4 + (srow & 3);
  const int kkey = (sgi ^ (prow & 7)) * 8;
  const int vkey = (sgi ^ (srow & 7)) * 8;
  const unsigned short* kbase = kk_ + ((size_t)bh * T_ + srow) * 64 + sgi * 8;
  const unsigned short* vrow0 = vt + ((size_t)(bh * 64 + srow)) * T_;
  const unsigned short* vrow1 = vrow0 + (size_t)32 * T_;
  const int vco0 = sgi * 8;
  const int vco1 = ((sgi ^ 2) * 8) + 4;

  const int tw = t0 + w * 16;

  bf16x8 qf[2];
  const unsigned short* qb = q + ((size_t)(bh * T_ + tw + lo)) * 64;
  #pragma unroll
  for (int kd = 0; kd < 2; ++kd)
    qf[kd] = *(const bf16x8*)(qb + kd * 32 + g * 8);

  const int sb0 = g * 8, sb1 = ((g ^ 2) * 8) + 4;

  union { unsigned u[4]; bf16x8 v; } onec;
  onec.u[0] = onec.u[1] = onec.u[2] = onec.u[3] = 0x3f803f80u;
  const bf16x8 onesv = onec.v;

  float m_ = -1e30f;
  f32x4 zero4 = {0.f, 0.f, 0.f, 0.f};
  f32x4 lacc = zero4;
  f32x4 oacc[4];
  #pragma unroll
  for (int dt = 0; dt < 4; ++dt) oacc[dt] = zero4;

  const int nsteps = qt + 1;
  union u8c { us4 h4[2]; us8 v; };
  us8 kr0 = *(const us8*)(kbase);
  us8 kr1 = *(const us8*)(kbase + 2048);
  u8c vr0, vr1;
  vr0.h4[0] = *(const us4*)(vrow0 + vco0);
  vr0.h4[1] = *(const us4*)(vrow0 + vco1);
  vr1.h4[0] = *(const us4*)(vrow1 + vco0);
  vr1.h4[1] = *(const us4*)(vrow1 + vco1);
  *(us8*)&Kl[0][prow][kkey] = kr0;
  *(us8*)&Kl[0][prow + 32][kkey] = kr1;
  *(us8*)&Vl[0][srow][vkey] = vr0.v;
  *(us8*)&Vl[0][srow + 32][vkey] = vr1.v;
  if (nsteps > 1) {
    kr0 = *(const us8*)(kbase + 4096);
    kr1 = *(const us8*)(kbase + 4096 + 2048);
    vr0.h4[0] = *(const us4*)(vrow0 + 64 + vco0);
    vr0.h4[1] = *(const us4*)(vrow0 + 64 + vco1);
    vr1.h4[0] = *(const us4*)(vrow1 + 64 + vco0);
    vr1.h4[1] = *(const us4*)(vrow1 + 64 + vco1);
  }
  __syncthreads();

  bf16x8 pb[2];
  int vprev = 0;

  for (int stp = 0; stp < nsteps; ++stp) {
    const int cur = stp & 1;
    us8 nk0, nk1;
    u8c nv0, nv1;
    const bool pf = (stp + 2 < nsteps);
    if (pf) {
      const size_t ko_ = (size_t)(stp + 2) * 4096;
      const int so = (stp + 2) * 64;
      nk0 = *(const us8*)(kbase + ko_);
      nk1 = *(const us8*)(kbase + ko_ + 2048);
      nv0.h4[0] = *(const us4*)(vrow0 + so + vco0);
      nv0.h4[1] = *(const us4*)(vrow0 + so + vco1);
      nv1.h4[0] = *(const us4*)(vrow1 + so + vco0);
      nv1.h4[1] = *(const us4*)(vrow1 + so + vco1);
    }
    f32x4 sacc[4];
    #pragma unroll
    for (int ss = 0; ss < 4; ++ss) sacc[ss] = zero4;
    __builtin_amdgcn_s_setprio(1);
    #pragma unroll
    for (int ss = 0; ss < 4; ++ss) {
      bf16x8 ka0 = *(const bf16x8*)&Kl[cur][ss * 16 + lo][(g ^ rs) * 8];
      bf16x8 ka1 = *(const bf16x8*)&Kl[cur][ss * 16 + lo][((g | 4) ^ rs) * 8];
      sacc[ss] = mfma16(ka0, qf[0], sacc[ss]);
      sacc[ss] = mfma16(ka1, qf[1], sacc[ss]);
    }
    if (stp > 0) {
      #pragma unroll
      for (int kh = 0; kh < 2; ++kh) {
        #pragma unroll
        for (int dt = 0; dt < 4; ++dt) {
          bf16x8 va = *(const bf16x8*)&Vl[vprev][dt * 16 + lo][((kh * 4 + g) ^ rs) * 8];
          oacc[dt] = mfma16(va, pb[kh], oacc[dt]);
        }
      }
    }
    __builtin_amdgcn_s_setprio(0);
    if (stp == nsteps - 1) {
      #pragma unroll
      for (int ss = 0; ss < 4; ++ss) {
        const int sb = ((ss & 1) ? sb1 : sb0) + (ss >> 1) * 32;
        #pragma unroll
        for (int r = 0; r < 4; ++r) {
          if (t0 + sb + r > tw + lo) sacc[ss][r] = -1e30f;
        }
      }
    }
    float mx = -1e30f;
    #pragma unroll
    for (int ss = 0; ss < 4; ++ss) {
      float a = fmaxf(sacc[ss][0], sacc[ss][1]);
      float c = fmaxf(sacc[ss][2], sacc[ss][3]);
      mx = fmaxf(mx, fmaxf(a, c));
    }
    if (!__all(mx <= m_ + 8.0f)) {
      mx = fmaxf(mx, __shfl_xor(mx, 16));
      mx = fmaxf(mx, __shfl_xor(mx, 32));
      float mn = fmaxf(m_, mx);
      float corr = fexp2(m_ - mn);
      m_ = mn;
      lacc *= corr;
      #pragma unroll
      for (int dt = 0; dt < 4; ++dt) oacc[dt] *= corr;
    }
    #pragma unroll
    for (int kh = 0; kh < 2; ++kh) {
      union { unsigned u[4]; bf16x8 v; } pbc;
      #pragma unroll
      for (int half2 = 0; half2 < 2; ++half2) {
        const int ss = kh * 2 + half2;
        float p0 = fexp2(sacc[ss][0] - m_);
        float p1 = fexp2(sacc[ss][1] - m_);
        float p2 = fexp2(sacc[ss][2] - m_);
        float p3 = fexp2(sacc[ss][3] - m_);
        pbc.u[half2 * 2]     = pkw(p0, p1);
        pbc.u[half2 * 2 + 1] = pkw(p2, p3);
      }
      pb[kh] = pbc.v;
      lacc = mfma16(onesv, pb[kh], lacc);
    }
    vprev = stp % 3;
    if (stp + 1 < nsteps) {
      *(us8*)&Kl[cur ^ 1][prow][kkey] = kr0;
      *(us8*)&Kl[cur ^ 1][prow + 32][kkey] = kr1;
      const int vn = (stp + 1) % 3;
      *(us8*)&Vl[vn][srow][vkey] = vr0.v;
      *(us8*)&Vl[vn][srow + 32][vkey] = vr1.v;
    }
    __syncthreads();
    if (pf) { kr0 = nk0; kr1 = nk1; vr0 = nv0; vr1 = nv1; }
  }
  __builtin_amdgcn_s_setprio(1);
  #pragma unroll
  for (int kh = 0; kh < 2; ++kh) {
    #pragma unroll
    for (int dt = 0; dt < 4; ++dt) {
      bf16x8 va = *(const bf16x8*)&Vl[vprev][dt * 16 + lo][((kh * 4 + g) ^ rs) * 8];
      oacc[dt] = mfma16(va, pb[kh], oacc[dt]);
    }
  }
  __builtin_amdgcn_s_setprio(0);
  float inv = 1.0f / lacc[0];
  unsigned short* op = ao + ((size_t)(b * T_ + tw + lo)) * E_ + h * 64;
  #pragma unroll
  for (int dt = 0; dt < 4; ++dt) {
    us4 pk;
    #pragma unroll
    for (int r = 0; r < 4; ++r) pk[r] = f2b(oacc[dt][r] * inv);
    *(us4*)(op + dt * 16 + g * 4) = pk;
  }
}

// ---------------- output projection v3: BK=64, 16 iters, XCD-partitioned ----------------
__launch_bounds__(256)
__global__ void proj_kernel(const unsigned short* __restrict__ ao,
                            const unsigned short* __restrict__ wpb,
                            const float* __restrict__ bp,
                            float* __restrict__ out)
{
  const int bid = blockIdx.x;
  const int xcd = bid & 7, idx = bid >> 3;
  const int m0 = (xcd * 4 + (idx & 3)) * 128;
  const int n0 = (idx >> 2) * 64;
  __shared__ unsigned short Al[2][128][72];
  __shared__ unsigned short Bl[2][64][72];
  const int tid = threadIdx.x, w = tid >> 6, lane = tid & 63, lo = lane & 15, g = lane >> 4;
  const int wr = (w >> 1) * 64, wc = (w & 1) * 32;
  f32x4 zero4 = {0.f, 0.f, 0.f, 0.f};
  f32x4 acc[4][2];
  #pragma unroll
  for (int i = 0; i < 4; ++i)
    #pragma unroll
    for (int j = 0; j < 2; ++j) acc[i][j] = zero4;

  const int arow = tid >> 1, acol = (tid & 1) * 32;
  const int brow = tid >> 2, bcol = (tid & 3) * 16;
  const unsigned short* abase = ao + (size_t)(m0 + arow) * 1024 + acol;
  const unsigned short* bbase = wpb + (size_t)(n0 + brow) * 1024 + bcol;

  us8 a0, a1, a2, a3, b0, b1;
  a0 = *(const us8*)(abase);
  a1 = *(const us8*)(abase + 8);
  a2 = *(const us8*)(abase + 16);
  a3 = *(const us8*)(abase + 24);
  b0 = *(const us8*)(bbase);
  b1 = *(const us8*)(bbase + 8);
  *(us8*)&Al[0][arow][acol] = a0;
  *(us8*)&Al[0][arow][acol + 8] = a1;
  *(us8*)&Al[0][arow][acol + 16] = a2;
  *(us8*)&Al[0][arow][acol + 24] = a3;
  *(us8*)&Bl[0][brow][bcol] = b0;
  *(us8*)&Bl[0][brow][bcol + 8] = b1;
  a0 = *(const us8*)(abase + 64);
  a1 = *(const us8*)(abase + 72);
  a2 = *(const us8*)(abase + 80);
  a3 = *(const us8*)(abase + 88);
  b0 = *(const us8*)(bbase + 64);
  b1 = *(const us8*)(bbase + 72);
  __syncthreads();

  for (int it = 0; it < 16; ++it) {
    const int cur = it & 1;
    us8 na0, na1, na2, na3, nb0, nb1;
    const bool pf = (it + 2 < 16);
    if (pf) {
      const int kn = (it + 2) * 64;
      na0 = *(const us8*)(abase + kn);
      na1 = *(const us8*)(abase + kn + 8);
      na2 = *(const us8*)(abase + kn + 16);
      na3 = *(const us8*)(abase + kn + 24);
      nb0 = *(const us8*)(bbase + kn);
      nb1 = *(const us8*)(bbase + kn + 8);
    }
    bf16x8 af[4][2], bfr[2][2];
    #pragma unroll
    for (int kk = 0; kk < 2; ++kk) {
      #pragma unroll
      for (int i = 0; i < 4; ++i)
        af[i][kk] = *(const bf16x8*)&Al[cur][wr + i * 16 + lo][kk * 32 + g * 8];
      #pragma unroll
      for (int j = 0; j < 2; ++j)
        bfr[j][kk] = *(const bf16x8*)&Bl[cur][wc + j * 16 + lo][kk * 32 + g * 8];
    }
    __builtin_amdgcn_s_setprio(1);
    #pragma unroll
    for (int kk = 0; kk < 2; ++kk)
      #pragma unroll
      for (int i = 0; i < 4; ++i)
        #pragma unroll
        for (int j = 0; j < 2; ++j)
          acc[i][j] = mfma16(af[i][kk], bfr[j][kk], acc[i][j]);
    __builtin_amdgcn_s_setprio(0);
    if (it + 1 < 16) {
      *(us8*)&Al[cur ^ 1][arow][acol] = a0;
      *(us8*)&Al[cur ^ 1][arow][acol + 8] = a1;
      *(us8*)&Al[cur ^ 1][arow][acol + 16] = a2;
      *(us8*)&Al[cur ^ 1][arow][acol + 24] = a3;
      *(us8*)&Bl[cur ^ 1][brow][bcol] = b0;
      *(us8*)&Bl[cur ^ 1][brow][bcol + 8] = b1;
    }
    __syncthreads();
    if (pf) { a0 = na0; a1 = na1; a2 = na2; a3 = na3; b0 = nb0; b1 = nb1; }
  }
  #pragma unroll
  for (int j = 0; j < 2; ++j) {
    int n = n0 + wc + j * 16 + lo;
    float bias = bp[n];
    #pragma unroll
    for (int i = 0; i < 4; ++i) {
      #pragma unroll
      for (int r = 0; r < 4; ++r)
        out[(size_t)(m0 + wr + i * 16 + g * 4 + r) * 1024 + n] = acc[i][j][r] + bias;
    }
  }
}

extern "C" void kernel_launch(void* const* d_in, const int* in_sizes, int n_in,
                              void* d_out, int out_size, void* d_ws, size_t ws_size,
                              hipStream_t stream)
{
  const float* x  = (const float*)d_in[0];
  const float* Wq = (const float*)d_in[2];
  const float* bq = (const float*)d_in[3];
  const float* Wk = (const float*)d_in[4];
  const float* bk = (const float*)d_in[5];
  const float* Wv = (const float*)d_in[6];
  const float* bv = (const float*)d_in[7];
  const float* Wp = (const float*)d_in[8];
  const float* bp = (const float*)d_in[9];
  float* out = (float*)d_out;

  char* ws = (char*)d_ws;
  const size_t SZ = (size_t)2 * 16 * 2048 * 64 * 2;  // 8 MB per bf16 tensor
  unsigned short* q   = (unsigned short*)(ws);
  unsigned short* kb  = (unsigned short*)(ws + SZ);
  unsigned short* vt  = (unsigned short*)(ws + 2 * SZ);
  unsigned short* ao  = (unsigned short*)(ws + 3 * SZ);
  unsigned short* wpb = (unsigned short*)(ws + 4 * SZ);            // 2 MB
  unsigned short* wqb = (unsigned short*)(ws + 4 * SZ + 2097152);  // 128 KB each
  unsigned short* wkb = wqb + 65536;
  unsigned short* wvb = wqb + 131072;

  cvt_kernel<<<dim3(1216), 256, 0, stream>>>(Wq, Wk, Wv, Wp, wqb, wkb, wvb, wpb);
  qkv_kernel<<<dim3(32, 16), 256, 0, stream>>>(x, wqb, bq, wkb, bk, wvb, bv, q, kb, vt);
  flash_kernel<<<dim3(32, 32), 256, 0, stream>>>(q, kb, vt, ao);
  proj_kernel<<<dim3(512), 256, 0, stream>>>(ao, wpb, bp, out);
}